// Round 8
// baseline (683.063 us; speedup 1.0000x reference)
//
#include <hip/hip_runtime.h>

typedef _Float16 f16;
typedef __fp16 hf2 __attribute__((ext_vector_type(2)));
typedef _Float16 f16x4 __attribute__((ext_vector_type(4)));
typedef _Float16 f16x8 __attribute__((ext_vector_type(8)));
typedef float f32x4 __attribute__((ext_vector_type(4)));

typedef const __attribute__((address_space(1))) unsigned int guint;
typedef __attribute__((address_space(3))) unsigned int luint;
__device__ __forceinline__ void gl_lds16(const void* g, void* l) {
    __builtin_amdgcn_global_load_lds((guint*)g, (luint*)l, 16, 0, 0);
}
template <int N>
__device__ __forceinline__ void vmwait() {
    if constexpr (N == 6)       asm volatile("s_waitcnt vmcnt(6)" ::: "memory");
    else if constexpr (N == 4)  asm volatile("s_waitcnt vmcnt(4)" ::: "memory");
    else                        asm volatile("s_waitcnt vmcnt(0)" ::: "memory");
}
__device__ __forceinline__ void barrier_raw() { __builtin_amdgcn_s_barrier(); __builtin_amdgcn_sched_barrier(0); }

// ---------------- K0: convert + transpose 5 weight matrices (512x512) to f16 ----------------
__global__ __launch_bounds__(256) void wconv(const float* w0, const float* w1, const float* w2,
                                             const float* w3, const float* w4, f16* dst) {
    const float* src;
    switch (blockIdx.z) { case 0: src = w0; break; case 1: src = w1; break;
                          case 2: src = w2; break; case 3: src = w3; break; default: src = w4; }
    __shared__ float tile[32][33];
    int k0 = blockIdx.x * 32, n0 = blockIdx.y * 32;
    int t = threadIdx.x;
    int r = t >> 3, c4 = (t & 7) * 4;
    float4 v = *(const float4*)(src + (k0 + r) * 512 + n0 + c4);
    tile[r][c4 + 0] = v.x; tile[r][c4 + 1] = v.y; tile[r][c4 + 2] = v.z; tile[r][c4 + 3] = v.w;
    __syncthreads();
    f16x4 o;
    o[0] = (f16)tile[c4 + 0][r]; o[1] = (f16)tile[c4 + 1][r];
    o[2] = (f16)tile[c4 + 2][r]; o[3] = (f16)tile[c4 + 3][r];
    *(f16x4*)(dst + (size_t)blockIdx.z * 262144 + (n0 + r) * 512 + k0 + c4) = o;
}

// ---------------- K1: ring-3 counted-vmcnt GEMM (T3+T4), 128x128, BK=32, 4 waves 2x2 ----------------
// Per iter: vmwait(L) [L = 1 tile's issues, never 0 in loop] -> barrier -> stage(tk+2) -> compute(tk).
// LDS: fp32-A 72KB (2 blocks/CU), f16-A 48KB (3 blocks/CU).
// Swizzles (both-sides, verified R3/R5/R7): fp32 128B rows blk^=(row&7); f16 64B rows blk^=((row>>1)&3).
template <bool A16, bool RELU, bool O16>
__global__ __launch_bounds__(256) void gemm_r3(const void* __restrict__ Ap,
                                               const f16* __restrict__ Bt,
                                               const float* __restrict__ bias,
                                               void* __restrict__ Cp) {
    constexpr int ASZ = A16 ? 8192 : 16384;
    constexpr int BSZ = 8192;
    constexpr int BUF = ASZ + BSZ;
    constexpr int LIF = A16 ? 4 : 6;   // gl_lds issues per tile per thread
    __shared__ __align__(16) char smem[3 * BUF];

    // bijective XCD-chunk swizzle (nwg = 3072 divisible by 8); 4 N-tiles share an A-panel
    const int cpx = gridDim.x >> 3;
    const int orig = blockIdx.x;
    const int wgid = (orig & 7) * cpx + (orig >> 3);
    const int by = wgid & 3;
    const int bx = wgid >> 2;
    const int r0 = bx * 128, c0 = by * 128;

    const int t = threadIdx.x;
    const int j = t & 63, w = t >> 6;
    const int lr = j & 15, lq = j >> 4;
    const int wr = (w >> 1) * 64, wc = (w & 1) * 64;

    // staging sources (pre-swizzled logical blk so linear LDS dest == swizzled layout)
    const char* aSrc;
    if (A16) aSrc = (const char*)Ap + ((size_t)(r0 + (t >> 2)) * 512 + ((t & 3) ^ ((t >> 3) & 3)) * 8) * 2;
    else     aSrc = (const char*)Ap + ((size_t)(r0 + (t >> 3)) * 512 + ((t & 7) ^ ((t >> 3) & 7)) * 4) * 4;
    const char* bSrc = (const char*)Bt + ((size_t)(c0 + (t >> 2)) * 512 + ((t & 3) ^ ((t >> 3) & 3)) * 8) * 2;

    // fragment ds_read byte offsets within a buffer (kk-independent)
    int aoffL[4], aoffH[4], boff[4];
#pragma unroll
    for (int m = 0; m < 4; m++) {
        int row = wr + m * 16 + lr;
        if (A16) {
            aoffL[m] = row * 64 + ((lq ^ ((row >> 1) & 3)) << 4);
        } else {
            int s = row & 7;
            aoffL[m] = row * 128 + (((2 * lq) ^ s) << 4);
            aoffH[m] = row * 128 + (((2 * lq + 1) ^ s) << 4);
        }
    }
#pragma unroll
    for (int nb = 0; nb < 4; nb++) {
        int row = wc + nb * 16 + lr;
        boff[nb] = ASZ + row * 64 + ((lq ^ ((row >> 1) & 3)) << 4);
    }

    f32x4 acc[4][4] = {};

    auto stage = [&](int tk, int buf) {
        char* al_ = smem + buf * BUF + t * 16;
        if (A16) {
            const char* as_ = aSrc + (size_t)tk * 64;
            gl_lds16(as_, al_);
            gl_lds16(as_ + 65536, al_ + 4096);
        } else {
            const char* as_ = aSrc + (size_t)tk * 128;
            gl_lds16(as_, al_);
            gl_lds16(as_ + 65536, al_ + 4096);
            gl_lds16(as_ + 131072, al_ + 8192);
            gl_lds16(as_ + 196608, al_ + 12288);
        }
        const char* bs_ = bSrc + (size_t)tk * 64;
        char* bl_ = smem + buf * BUF + ASZ + t * 16;
        gl_lds16(bs_, bl_);
        gl_lds16(bs_ + 65536, bl_ + 4096);
    };

    auto compute = [&](int buf) {
        const char* sb_ = smem + buf * BUF;
        f16x8 av[4], bv[4];
#pragma unroll
        for (int m = 0; m < 4; m++) {
            if (A16) {
                av[m] = *(const f16x8*)(sb_ + aoffL[m]);
            } else {
                float4 x0 = *(const float4*)(sb_ + aoffL[m]);
                float4 x1 = *(const float4*)(sb_ + aoffH[m]);
                hf2 p0 = __builtin_amdgcn_cvt_pkrtz(x0.x, x0.y);
                hf2 p1 = __builtin_amdgcn_cvt_pkrtz(x0.z, x0.w);
                hf2 p2 = __builtin_amdgcn_cvt_pkrtz(x1.x, x1.y);
                hf2 p3 = __builtin_amdgcn_cvt_pkrtz(x1.z, x1.w);
                f16x8 h;
                h[0] = (f16)p0[0]; h[1] = (f16)p0[1]; h[2] = (f16)p1[0]; h[3] = (f16)p1[1];
                h[4] = (f16)p2[0]; h[5] = (f16)p2[1]; h[6] = (f16)p3[0]; h[7] = (f16)p3[1];
                av[m] = h;
            }
        }
#pragma unroll
        for (int nb = 0; nb < 4; nb++) bv[nb] = *(const f16x8*)(sb_ + boff[nb]);
        __builtin_amdgcn_s_setprio(1);
#pragma unroll
        for (int m = 0; m < 4; m++)
#pragma unroll
            for (int nb = 0; nb < 4; nb++)
                acc[m][nb] = __builtin_amdgcn_mfma_f32_16x16x32_f16(av[m], bv[nb], acc[m][nb], 0, 0, 0);
        __builtin_amdgcn_s_setprio(0);
    };

    // prologue: 2 tiles in flight
    stage(0, 0); stage(1, 1);

    int bufc = 0, bufs = 2;
#pragma unroll 1
    for (int tk = 0; tk < 14; ++tk) {
        vmwait<LIF>();          // tile tk landed; tile tk+1's LIF issues may remain in flight
        barrier_raw();          // all waves agree: buf[bufs] free (tile tk-1 consumed), tile tk visible
        stage(tk + 2, bufs);
        compute(bufc);
        bufc = (bufc == 2) ? 0 : bufc + 1;
        bufs = (bufs == 2) ? 0 : bufs + 1;
    }
    vmwait<LIF>(); barrier_raw(); compute(2);   // tk=14 (14%3==2)
    vmwait<0>();   barrier_raw(); compute(0);   // tk=15 (15%3==0)

#pragma unroll
    for (int nb = 0; nb < 4; nb++) {
        int col = c0 + wc + nb * 16 + lr;
        float b = bias[col];
#pragma unroll
        for (int m = 0; m < 4; m++) {
#pragma unroll
            for (int r = 0; r < 4; r++) {
                float v = acc[m][nb][r] + b;
                if (RELU) v = fmaxf(v, 0.0f);
                size_t row = (size_t)(r0 + wr + m * 16 + lq * 4 + r);
                if (O16) ((f16*)Cp)[row * 512 + col] = (f16)v;
                else     ((float*)Cp)[row * 512 + col] = v;
            }
        }
    }
}

// ---------------- K2: attention per (b,h,n). 1 wave/block. ----------------
__global__ __launch_bounds__(64) void attn_kernel(const f16* __restrict__ q,
                                                  const f16* __restrict__ k,
                                                  const f16* __restrict__ v,
                                                  f16* __restrict__ out) {
    const int h = blockIdx.x, n = blockIdx.y, b = blockIdx.z;
    __shared__ f16 sQ[48 * 72];
    __shared__ f16 sK[48 * 72];
    __shared__ f16 sP[48 * 72];   // [q=48][p padded to 64]
    __shared__ f16 sVt[64 * 72];  // [d=64][p padded to 64]
    const int l = threadIdx.x, lr = l & 15, lq = l >> 4;
    const size_t rowstride = 256 * 512;
    const size_t base = ((size_t)(b * 48) * 256 + n) * 512 + h * 64;

    const int pr = l >> 3, pc = (l & 7) * 8;
#pragma unroll
    for (int pass = 0; pass < 6; pass++) {
        int row = pass * 8 + pr;
        size_t g = base + (size_t)row * rowstride + pc;
        f16x8 qv = *(const f16x8*)(q + g);
        f16x8 kv = *(const f16x8*)(k + g);
        f16x8 vv = *(const f16x8*)(v + g);
        *(f16x8*)&sQ[row * 72 + pc] = qv;
        *(f16x8*)&sK[row * 72 + pc] = kv;
#pragma unroll
        for (int j = 0; j < 8; j++) sVt[(pc + j) * 72 + row] = vv[j];  // transpose V
    }
    {
        f16x8 z = {};
        *(f16x8*)&sVt[l * 72 + 48] = z;
        *(f16x8*)&sVt[l * 72 + 56] = z;
        if (l < 48) { *(f16x8*)&sP[l * 72 + 48] = z; *(f16x8*)&sP[l * 72 + 56] = z; }
    }
    __syncthreads();

    f32x4 s[3][3] = {};
#pragma unroll
    for (int ks = 0; ks < 2; ks++) {
        f16x8 aq[3], bk[3];
#pragma unroll
        for (int m = 0; m < 3; m++)  aq[m] = *(const f16x8*)&sQ[(m * 16 + lr) * 72 + ks * 32 + lq * 8];
#pragma unroll
        for (int nb = 0; nb < 3; nb++) bk[nb] = *(const f16x8*)&sK[(nb * 16 + lr) * 72 + ks * 32 + lq * 8];
#pragma unroll
        for (int m = 0; m < 3; m++)
#pragma unroll
            for (int nb = 0; nb < 3; nb++)
                s[m][nb] = __builtin_amdgcn_mfma_f32_16x16x32_f16(aq[m], bk[nb], s[m][nb], 0, 0, 0);
    }

#pragma unroll
    for (int m = 0; m < 3; m++) {
#pragma unroll
        for (int r = 0; r < 4; r++) {
            float a0 = s[m][0][r] * 0.125f, a1 = s[m][1][r] * 0.125f, a2 = s[m][2][r] * 0.125f;
            float mx = fmaxf(a0, fmaxf(a1, a2));
#pragma unroll
            for (int d = 1; d < 16; d <<= 1) mx = fmaxf(mx, __shfl_xor(mx, d));
            float e0 = __expf(a0 - mx), e1 = __expf(a1 - mx), e2 = __expf(a2 - mx);
            float sm = e0 + e1 + e2;
#pragma unroll
            for (int d = 1; d < 16; d <<= 1) sm += __shfl_xor(sm, d);
            float inv = 1.0f / sm;
            int row = m * 16 + lq * 4 + r;
            sP[row * 72 + 0  + lr] = (f16)(e0 * inv);
            sP[row * 72 + 16 + lr] = (f16)(e1 * inv);
            sP[row * 72 + 32 + lr] = (f16)(e2 * inv);
        }
    }
    __syncthreads();

    f32x4 o[3][4] = {};
#pragma unroll
    for (int ks = 0; ks < 2; ks++) {
        f16x8 ap[3], bvv[4];
#pragma unroll
        for (int m = 0; m < 3; m++)  ap[m] = *(const f16x8*)&sP[(m * 16 + lr) * 72 + ks * 32 + lq * 8];
#pragma unroll
        for (int nb = 0; nb < 4; nb++) bvv[nb] = *(const f16x8*)&sVt[(nb * 16 + lr) * 72 + ks * 32 + lq * 8];
#pragma unroll
        for (int m = 0; m < 3; m++)
#pragma unroll
            for (int nb = 0; nb < 4; nb++)
                o[m][nb] = __builtin_amdgcn_mfma_f32_16x16x32_f16(ap[m], bvv[nb], o[m][nb], 0, 0, 0);
    }

#pragma unroll
    for (int m = 0; m < 3; m++)
#pragma unroll
        for (int nb = 0; nb < 4; nb++)
#pragma unroll
            for (int r = 0; r < 4; r++) {
                int row = m * 16 + lq * 4 + r;
                out[base + (size_t)row * rowstride + nb * 16 + lr] = (f16)o[m][nb][r];
            }
}

// ---------------- launch ----------------
extern "C" void kernel_launch(void* const* d_in, const int* in_sizes, int n_in,
                              void* d_out, int out_size, void* d_ws, size_t ws_size,
                              hipStream_t stream) {
    const float* X    = (const float*)d_in[0];
    const float* STEP = (const float*)d_in[1];
    const float* STEQ = (const float*)d_in[2];
    const float* Wq   = (const float*)d_in[3];
    const float* bq   = (const float*)d_in[4];
    const float* Wk   = (const float*)d_in[5];
    const float* bk   = (const float*)d_in[6];
    const float* Wv   = (const float*)d_in[7];
    const float* bv   = (const float*)d_in[8];
    const float* W1   = (const float*)d_in[9];
    const float* b1   = (const float*)d_in[10];
    const float* W2   = (const float*)d_in[11];
    const float* b2   = (const float*)d_in[12];
    float* out = (float*)d_out;

    const size_t MROWS = 98304;           // B*TQ*N = 8*48*256
    f16* ws  = (f16*)d_ws;
    f16* Wqt = ws;                        // 512*512 each
    f16* Wkt = ws + 262144;
    f16* Wvt = ws + 524288;
    f16* W1t = ws + 786432;
    f16* W2t = ws + 1048576;
    f16* qb  = ws + 1310720;              // MROWS*512 f16
    f16* kb  = qb + MROWS * 512;
    f16* vb  = kb + MROWS * 512;
    f16* attn = qb;                       // attention writes in-place over q
    f16* hb   = kb;                       // FFN hidden reuses k buffer

    wconv<<<dim3(16, 16, 5), 256, 0, stream>>>(Wq, Wk, Wv, W1, W2, ws);

    gemm_r3<false, true, true><<<3072, 256, 0, stream>>>(STEQ, Wqt, bq, qb);
    gemm_r3<false, true, true><<<3072, 256, 0, stream>>>(STEP, Wkt, bk, kb);
    gemm_r3<false, true, true><<<3072, 256, 0, stream>>>(X,    Wvt, bv, vb);

    attn_kernel<<<dim3(8, 256, 8), 64, 0, stream>>>(qb, kb, vb, attn);

    gemm_r3<true, true,  true ><<<3072, 256, 0, stream>>>(attn, W1t, b1, hb);
    gemm_r3<true, false, false><<<3072, 256, 0, stream>>>(hb,   W2t, b2, out);
}

// Round 9
// 620.295 us; speedup vs baseline: 1.1012x; 1.1012x over previous
//
#include <hip/hip_runtime.h>

typedef _Float16 f16;
typedef __fp16 hf2 __attribute__((ext_vector_type(2)));
typedef _Float16 f16x4 __attribute__((ext_vector_type(4)));
typedef _Float16 f16x8 __attribute__((ext_vector_type(8)));
typedef float f32x4 __attribute__((ext_vector_type(4)));

typedef const __attribute__((address_space(1))) unsigned int guint;
typedef __attribute__((address_space(3))) unsigned int luint;
__device__ __forceinline__ void gl_lds16(const void* g, void* l) {
    __builtin_amdgcn_global_load_lds((guint*)g, (luint*)l, 16, 0, 0);
}
template <int N>
__device__ __forceinline__ void vmwait() {
    if constexpr (N == 8)       asm volatile("s_waitcnt vmcnt(8)" ::: "memory");
    else if constexpr (N == 4)  asm volatile("s_waitcnt vmcnt(4)" ::: "memory");
    else                        asm volatile("s_waitcnt vmcnt(0)" ::: "memory");
}
__device__ __forceinline__ void barrier_raw() { __builtin_amdgcn_s_barrier(); __builtin_amdgcn_sched_barrier(0); }

// ---------------- K0: convert + transpose 5 weight matrices (512x512) to f16 ----------------
__global__ __launch_bounds__(256) void wconv(const float* w0, const float* w1, const float* w2,
                                             const float* w3, const float* w4, f16* dst) {
    const float* src;
    switch (blockIdx.z) { case 0: src = w0; break; case 1: src = w1; break;
                          case 2: src = w2; break; case 3: src = w3; break; default: src = w4; }
    __shared__ float tile[32][33];
    int k0 = blockIdx.x * 32, n0 = blockIdx.y * 32;
    int t = threadIdx.x;
    int r = t >> 3, c4 = (t & 7) * 4;
    float4 v = *(const float4*)(src + (k0 + r) * 512 + n0 + c4);
    tile[r][c4 + 0] = v.x; tile[r][c4 + 1] = v.y; tile[r][c4 + 2] = v.z; tile[r][c4 + 3] = v.w;
    __syncthreads();
    f16x4 o;
    o[0] = (f16)tile[c4 + 0][r]; o[1] = (f16)tile[c4 + 1][r];
    o[2] = (f16)tile[c4 + 2][r]; o[3] = (f16)tile[c4 + 3][r];
    *(f16x4*)(dst + (size_t)blockIdx.z * 262144 + (n0 + r) * 512 + k0 + c4) = o;
}

// ---------------- K1a (QKV, fp32-A): R7 structure verbatim (best measured: 140 us) ----------------
template <bool A16, bool RELU, bool O16>
__global__ __launch_bounds__(512) void gemm_w8(const void* __restrict__ Ap,
                                               const f16* __restrict__ Bt,
                                               const float* __restrict__ bias,
                                               void* __restrict__ Cp) {
    constexpr int ASZ = A16 ? 16384 : 32768;
    constexpr int BSZ = 8192;
    constexpr int BUF = ASZ + BSZ;
    __shared__ __align__(16) char smem[2 * BUF];

    const int cpx = gridDim.x >> 3;
    const int orig = blockIdx.x;
    const int wgid = (orig & 7) * cpx + (orig >> 3);
    const int by = wgid & 3;
    const int bx = wgid >> 2;
    const int r0 = bx * 256, c0 = by * 128;

    const int t = threadIdx.x;
    const int j = t & 63, w = t >> 6;
    const int lr = j & 15, lq = j >> 4;
    const int wr = (w >> 1) * 64, wc = (w & 1) * 64;

    const char* aSrc;
    if (A16) aSrc = (const char*)Ap + ((size_t)(r0 + (t >> 2)) * 512 + ((t & 3) ^ ((t >> 3) & 3)) * 8) * 2;
    else     aSrc = (const char*)Ap + ((size_t)(r0 + (t >> 3)) * 512 + ((t & 7) ^ ((t >> 3) & 7)) * 4) * 4;
    const char* bSrc = (const char*)Bt + ((size_t)(c0 + (t >> 2)) * 512 + ((t & 3) ^ ((t >> 3) & 3)) * 8) * 2;

    int aoffL[4], aoffH[4], boff[4];
#pragma unroll
    for (int m = 0; m < 4; m++) {
        int row = wr + m * 16 + lr;
        if (A16) {
            aoffL[m] = row * 64 + ((lq ^ ((row >> 1) & 3)) << 4);
        } else {
            int s = row & 7;
            aoffL[m] = row * 128 + (((2 * lq) ^ s) << 4);
            aoffH[m] = row * 128 + (((2 * lq + 1) ^ s) << 4);
        }
    }
#pragma unroll
    for (int nb = 0; nb < 4; nb++) {
        int row = wc + nb * 16 + lr;
        boff[nb] = ASZ + row * 64 + ((lq ^ ((row >> 1) & 3)) << 4);
    }

    f32x4 acc[4][4] = {};

#define STAGE(tk, buf)                                                     \
    do {                                                                   \
        char* al_ = smem + (buf) * BUF + t * 16;                           \
        if (A16) {                                                         \
            const char* as_ = aSrc + (size_t)(tk) * 64;                    \
            gl_lds16(as_, al_);                                            \
            gl_lds16(as_ + 131072, al_ + 8192);                            \
        } else {                                                           \
            const char* as_ = aSrc + (size_t)(tk) * 128;                   \
            gl_lds16(as_, al_);                                            \
            gl_lds16(as_ + 131072, al_ + 8192);                            \
            gl_lds16(as_ + 262144, al_ + 16384);                           \
            gl_lds16(as_ + 393216, al_ + 24576);                           \
        }                                                                  \
        const char* bs_ = bSrc + (size_t)(tk) * 64;                        \
        gl_lds16(bs_, smem + (buf) * BUF + ASZ + t * 16);                  \
    } while (0)

#define COMPUTE(buf)                                                       \
    do {                                                                   \
        const char* sb_ = smem + (buf) * BUF;                              \
        f16x8 av[4], bv[4];                                                \
        _Pragma("unroll")                                                  \
        for (int m = 0; m < 4; m++) {                                      \
            if (A16) {                                                     \
                av[m] = *(const f16x8*)(sb_ + aoffL[m]);                   \
            } else {                                                       \
                float4 x0 = *(const float4*)(sb_ + aoffL[m]);              \
                float4 x1 = *(const float4*)(sb_ + aoffH[m]);              \
                hf2 p0 = __builtin_amdgcn_cvt_pkrtz(x0.x, x0.y);           \
                hf2 p1 = __builtin_amdgcn_cvt_pkrtz(x0.z, x0.w);           \
                hf2 p2 = __builtin_amdgcn_cvt_pkrtz(x1.x, x1.y);           \
                hf2 p3 = __builtin_amdgcn_cvt_pkrtz(x1.z, x1.w);           \
                f16x8 h;                                                   \
                h[0] = (f16)p0[0]; h[1] = (f16)p0[1]; h[2] = (f16)p1[0]; h[3] = (f16)p1[1]; \
                h[4] = (f16)p2[0]; h[5] = (f16)p2[1]; h[6] = (f16)p3[0]; h[7] = (f16)p3[1]; \
                av[m] = h;                                                 \
            }                                                              \
        }                                                                  \
        _Pragma("unroll")                                                  \
        for (int nb = 0; nb < 4; nb++) bv[nb] = *(const f16x8*)(sb_ + boff[nb]); \
        _Pragma("unroll")                                                  \
        for (int m = 0; m < 4; m++)                                        \
            _Pragma("unroll")                                              \
            for (int nb = 0; nb < 4; nb++)                                 \
                acc[m][nb] = __builtin_amdgcn_mfma_f32_16x16x32_f16(av[m], bv[nb], acc[m][nb], 0, 0, 0); \
    } while (0)

    STAGE(0, 0);
    __syncthreads();
    int cur = 0;
#pragma unroll 1
    for (int tk = 0; tk < 16; ++tk) {
        if (tk < 15) STAGE(tk + 1, cur ^ 1);
        COMPUTE(cur);
        __syncthreads();
        cur ^= 1;
    }
#undef STAGE
#undef COMPUTE

#pragma unroll
    for (int nb = 0; nb < 4; nb++) {
        int col = c0 + wc + nb * 16 + lr;
        float b = bias[col];
#pragma unroll
        for (int m = 0; m < 4; m++) {
#pragma unroll
            for (int r = 0; r < 4; r++) {
                float v = acc[m][nb][r] + b;
                if (RELU) v = fmaxf(v, 0.0f);
                size_t row = (size_t)(r0 + wr + m * 16 + lq * 4 + r);
                if (O16) ((f16*)Cp)[row * 512 + col] = (f16)v;
                else     ((float*)Cp)[row * 512 + col] = v;
            }
        }
    }
}

// ---------------- K1b (FFN, f16-A): 8-phase counted-vmcnt GEMM (T3+T4+T5) ----------------
// BM=256, BN=256, BK=32, 8 waves (2m x 4n; wave tile 128x64), 4-buffer ring 4x32KB = 128KB.
// Per K-tile: 2 phases of {vmwait -> barrier -> stage 2 half-tiles of kt+3 -> ds_read frags -> 16 MFMA}.
// Steady vmcnt(8) = 2 tiles x 4 issues in flight; prefetch distance 6 phases. Swizzle blk^=((row>>1)&3).
template <bool RELU, bool O16>
__global__ __launch_bounds__(512, 2) void gemm_8ph(const f16* __restrict__ A,
                                                   const f16* __restrict__ Bt,
                                                   const float* __restrict__ bias,
                                                   void* __restrict__ Cp) {
    constexpr int BUFSZ = 32768;   // A 16KB + B 16KB
    __shared__ __align__(16) char smem[4 * BUFSZ];

    // XCD swizzle; nwg = 768 (div by 8). by in {0,1}: 2 N-tiles of 256.
    const int cpx = gridDim.x >> 3;
    const int orig = blockIdx.x;
    const int wgid = (orig & 7) * cpx + (orig >> 3);
    const int by = wgid & 1;
    const int bx = wgid >> 1;
    const int r0 = bx * 256, c0 = by * 256;

    const int t = threadIdx.x;
    const int j = t & 63, w = t >> 6;          // 8 waves
    const int lr = j & 15, lq = j >> 4;
    const int wr = (w >> 2) * 128, wc = (w & 3) * 64;

    // staging: linear LDS dest (t*16), pre-swizzled global source. Half = 128 rows x 64B = 8KB = 1 issue.
    const int srow = t >> 2;                   // 0..127
    const int sblk = (t & 3) ^ ((t >> 3) & 3); // involution of ((row>>1)&3) with row = t>>2
    const f16* aS = A  + (size_t)(r0 + srow) * 512 + sblk * 8;
    const f16* bS = Bt + (size_t)(c0 + srow) * 512 + sblk * 8;
    const int dstT = t * 16;

    // fragment ds_read byte offsets (within a buffer)
    int aoff[8], boff[4];
#pragma unroll
    for (int m = 0; m < 8; m++) {
        int row = wr + m * 16 + lr;
        aoff[m] = row * 64 + ((lq ^ ((row >> 1) & 3)) << 4);
    }
#pragma unroll
    for (int nb = 0; nb < 4; nb++) {
        int row = wc + nb * 16 + lr;
        boff[nb] = 16384 + row * 64 + ((lq ^ ((row >> 1) & 3)) << 4);
    }

    f32x4 acc[8][4] = {};

    auto stageA = [&](int kt) {
        char* d = smem + (kt & 3) * BUFSZ + dstT;
        const f16* s = aS + kt * 32;
        gl_lds16(s, d);                 // rows 0-127
        gl_lds16(s + 65536, d + 8192);  // rows 128-255
    };
    auto stageB = [&](int kt) {
        char* d = smem + (kt & 3) * BUFSZ + 16384 + dstT;
        const f16* s = bS + kt * 32;
        gl_lds16(s, d);
        gl_lds16(s + 65536, d + 8192);
    };

    // prologue: tiles 0,1,2 fully staged (12 issues)
    stageA(0); stageB(0); stageA(1); stageB(1); stageA(2); stageB(2);

#pragma unroll 1
    for (int kt = 0; kt < 16; ++kt) {
        const char* sb = smem + (kt & 3) * BUFSZ;
        // ---- phase A: m-frags 0-3 x all n ----
        if (kt <= 13)      vmwait<8>();
        else if (kt == 14) vmwait<4>();
        else               vmwait<0>();
        barrier_raw();
        if (kt < 13) stageA(kt + 3);
        f16x8 bfr[4], afr[4];
#pragma unroll
        for (int nb = 0; nb < 4; nb++) bfr[nb] = *(const f16x8*)(sb + boff[nb]);
#pragma unroll
        for (int m = 0; m < 4; m++) afr[m] = *(const f16x8*)(sb + aoff[m]);
        __builtin_amdgcn_s_setprio(1);
#pragma unroll
        for (int m = 0; m < 4; m++)
#pragma unroll
            for (int nb = 0; nb < 4; nb++)
                acc[m][nb] = __builtin_amdgcn_mfma_f32_16x16x32_f16(afr[m], bfr[nb], acc[m][nb], 0, 0, 0);
        __builtin_amdgcn_s_setprio(0);
        barrier_raw();
        // ---- phase B: m-frags 4-7 x all n (B reused in regs) ----
        if (kt < 13) stageB(kt + 3);
        f16x8 afr2[4];
#pragma unroll
        for (int m = 0; m < 4; m++) afr2[m] = *(const f16x8*)(sb + aoff[m + 4]);
        __builtin_amdgcn_s_setprio(1);
#pragma unroll
        for (int m = 0; m < 4; m++)
#pragma unroll
            for (int nb = 0; nb < 4; nb++)
                acc[m + 4][nb] = __builtin_amdgcn_mfma_f32_16x16x32_f16(afr2[m], bfr[nb], acc[m + 4][nb], 0, 0, 0);
        __builtin_amdgcn_s_setprio(0);
        // no trailing barrier: next iteration's phase-A barrier orders buf reuse
    }

#pragma unroll
    for (int nb = 0; nb < 4; nb++) {
        int col = c0 + wc + nb * 16 + lr;
        float b = bias[col];
#pragma unroll
        for (int m = 0; m < 8; m++) {
#pragma unroll
            for (int r = 0; r < 4; r++) {
                float v = acc[m][nb][r] + b;
                if (RELU) v = fmaxf(v, 0.0f);
                size_t row = (size_t)(r0 + wr + m * 16 + lq * 4 + r);
                if (O16) ((f16*)Cp)[row * 512 + col] = (f16)v;
                else     ((float*)Cp)[row * 512 + col] = v;
            }
        }
    }
}

// ---------------- K2: attention per (b,h,n). 1 wave/block. ----------------
__global__ __launch_bounds__(64) void attn_kernel(const f16* __restrict__ q,
                                                  const f16* __restrict__ k,
                                                  const f16* __restrict__ v,
                                                  f16* __restrict__ out) {
    const int h = blockIdx.x, n = blockIdx.y, b = blockIdx.z;
    __shared__ f16 sQ[48 * 72];
    __shared__ f16 sK[48 * 72];
    __shared__ f16 sP[48 * 72];
    __shared__ f16 sVt[64 * 72];
    const int l = threadIdx.x, lr = l & 15, lq = l >> 4;
    const size_t rowstride = 256 * 512;
    const size_t base = ((size_t)(b * 48) * 256 + n) * 512 + h * 64;

    const int pr = l >> 3, pc = (l & 7) * 8;
#pragma unroll
    for (int pass = 0; pass < 6; pass++) {
        int row = pass * 8 + pr;
        size_t g = base + (size_t)row * rowstride + pc;
        f16x8 qv = *(const f16x8*)(q + g);
        f16x8 kv = *(const f16x8*)(k + g);
        f16x8 vv = *(const f16x8*)(v + g);
        *(f16x8*)&sQ[row * 72 + pc] = qv;
        *(f16x8*)&sK[row * 72 + pc] = kv;
#pragma unroll
        for (int jj = 0; jj < 8; jj++) sVt[(pc + jj) * 72 + row] = vv[jj];
    }
    {
        f16x8 z = {};
        *(f16x8*)&sVt[l * 72 + 48] = z;
        *(f16x8*)&sVt[l * 72 + 56] = z;
        if (l < 48) { *(f16x8*)&sP[l * 72 + 48] = z; *(f16x8*)&sP[l * 72 + 56] = z; }
    }
    __syncthreads();

    f32x4 s[3][3] = {};
#pragma unroll
    for (int ks = 0; ks < 2; ks++) {
        f16x8 aq[3], bk[3];
#pragma unroll
        for (int m = 0; m < 3; m++)  aq[m] = *(const f16x8*)&sQ[(m * 16 + lr) * 72 + ks * 32 + lq * 8];
#pragma unroll
        for (int nb = 0; nb < 3; nb++) bk[nb] = *(const f16x8*)&sK[(nb * 16 + lr) * 72 + ks * 32 + lq * 8];
#pragma unroll
        for (int m = 0; m < 3; m++)
#pragma unroll
            for (int nb = 0; nb < 3; nb++)
                s[m][nb] = __builtin_amdgcn_mfma_f32_16x16x32_f16(aq[m], bk[nb], s[m][nb], 0, 0, 0);
    }

#pragma unroll
    for (int m = 0; m < 3; m++) {
#pragma unroll
        for (int r = 0; r < 4; r++) {
            float a0 = s[m][0][r] * 0.125f, a1 = s[m][1][r] * 0.125f, a2 = s[m][2][r] * 0.125f;
            float mx = fmaxf(a0, fmaxf(a1, a2));
#pragma unroll
            for (int d = 1; d < 16; d <<= 1) mx = fmaxf(mx, __shfl_xor(mx, d));
            float e0 = __expf(a0 - mx), e1 = __expf(a1 - mx), e2 = __expf(a2 - mx);
            float sm = e0 + e1 + e2;
#pragma unroll
            for (int d = 1; d < 16; d <<= 1) sm += __shfl_xor(sm, d);
            float inv = 1.0f / sm;
            int row = m * 16 + lq * 4 + r;
            sP[row * 72 + 0  + lr] = (f16)(e0 * inv);
            sP[row * 72 + 16 + lr] = (f16)(e1 * inv);
            sP[row * 72 + 32 + lr] = (f16)(e2 * inv);
        }
    }
    __syncthreads();

    f32x4 o[3][4] = {};
#pragma unroll
    for (int ks = 0; ks < 2; ks++) {
        f16x8 ap[3], bvv[4];
#pragma unroll
        for (int m = 0; m < 3; m++)  ap[m] = *(const f16x8*)&sP[(m * 16 + lr) * 72 + ks * 32 + lq * 8];
#pragma unroll
        for (int nb = 0; nb < 4; nb++) bvv[nb] = *(const f16x8*)&sVt[(nb * 16 + lr) * 72 + ks * 32 + lq * 8];
#pragma unroll
        for (int m = 0; m < 3; m++)
#pragma unroll
            for (int nb = 0; nb < 4; nb++)
                o[m][nb] = __builtin_amdgcn_mfma_f32_16x16x32_f16(ap[m], bvv[nb], o[m][nb], 0, 0, 0);
    }

#pragma unroll
    for (int m = 0; m < 3; m++)
#pragma unroll
        for (int nb = 0; nb < 4; nb++)
#pragma unroll
            for (int r = 0; r < 4; r++) {
                int row = m * 16 + lq * 4 + r;
                out[base + (size_t)row * rowstride + nb * 16 + lr] = (f16)o[m][nb][r];
            }
}

// ---------------- launch ----------------
extern "C" void kernel_launch(void* const* d_in, const int* in_sizes, int n_in,
                              void* d_out, int out_size, void* d_ws, size_t ws_size,
                              hipStream_t stream) {
    const float* X    = (const float*)d_in[0];
    const float* STEP = (const float*)d_in[1];
    const float* STEQ = (const float*)d_in[2];
    const float* Wq   = (const float*)d_in[3];
    const float* bq   = (const float*)d_in[4];
    const float* Wk   = (const float*)d_in[5];
    const float* bk   = (const float*)d_in[6];
    const float* Wv   = (const float*)d_in[7];
    const float* bv   = (const float*)d_in[8];
    const float* W1   = (const float*)d_in[9];
    const float* b1   = (const float*)d_in[10];
    const float* W2   = (const float*)d_in[11];
    const float* b2   = (const float*)d_in[12];
    float* out = (float*)d_out;

    const size_t MROWS = 98304;           // B*TQ*N = 8*48*256
    f16* ws  = (f16*)d_ws;
    f16* Wqt = ws;                        // 512*512 each
    f16* Wkt = ws + 262144;
    f16* Wvt = ws + 524288;
    f16* W1t = ws + 786432;
    f16* W2t = ws + 1048576;
    f16* qb  = ws + 1310720;              // MROWS*512 f16
    f16* kb  = qb + MROWS * 512;
    f16* vb  = kb + MROWS * 512;
    f16* attn = qb;                       // attention writes in-place over q
    f16* hb   = kb;                       // FFN hidden reuses k buffer

    wconv<<<dim3(16, 16, 5), 256, 0, stream>>>(Wq, Wk, Wv, W1, W2, ws);

    gemm_w8<false, true, true><<<1536, 512, 0, stream>>>(STEQ, Wqt, bq, qb);
    gemm_w8<false, true, true><<<1536, 512, 0, stream>>>(STEP, Wkt, bk, kb);
    gemm_w8<false, true, true><<<1536, 512, 0, stream>>>(X,    Wvt, bv, vb);

    attn_kernel<<<dim3(8, 256, 8), 64, 0, stream>>>(qb, kb, vb, attn);

    gemm_8ph<true,  true ><<<768, 512, 0, stream>>>(attn, W1t, b1, hb);
    gemm_8ph<false, false><<<768, 512, 0, stream>>>(hb,   W2t, b2, out);
}